// Round 11
// baseline (5359.763 us; speedup 1.0000x reference)
//
#include <hip/hip_runtime.h>
#include <stdint.h>

typedef short short8 __attribute__((ext_vector_type(8)));
typedef short short4v __attribute__((ext_vector_type(4)));
typedef float floatx4 __attribute__((ext_vector_type(4)));

#define LOG2E 1.44269504088896340736f

__device__ __forceinline__ float bf2f(unsigned short u) {
  unsigned v = ((unsigned)u) << 16;
  return __builtin_bit_cast(float, v);
}
__device__ __forceinline__ unsigned short f2bf(float f) {
  unsigned v = __builtin_bit_cast(unsigned, f);
  v += 0x7FFFu + ((v >> 16) & 1u);   // RNE
  return (unsigned short)(v >> 16);
}
__device__ __forceinline__ float fast_exp2(float x) {
#if __has_builtin(__builtin_amdgcn_exp2f)
  return __builtin_amdgcn_exp2f(x);
#else
  return exp2f(x);
#endif
}
__device__ __forceinline__ float fast_rcp(float x) {
#if __has_builtin(__builtin_amdgcn_rcpf)
  return __builtin_amdgcn_rcpf(x);
#else
  return 1.0f / x;
#endif
}
__device__ __forceinline__ float fsig(float x) {
  return fast_rcp(1.0f + fast_exp2(-LOG2E * x));
}
__device__ __forceinline__ floatx4 mfma16(short8 a, short8 b, floatx4 c) {
  return __builtin_amdgcn_mfma_f32_16x16x32_bf16(a, b, c, 0, 0, 0);
}

// ---------------------------------------------------------------------------
// Dtype detection: f32 buffers show even-u16 "exponent" >= 0xF0 often; bf16
// 0.05-scaled weights never do. flag: 1 = f32, 0 = bf16.
// ---------------------------------------------------------------------------
__global__ __launch_bounds__(256) void detect_kernel(
    const unsigned short* __restrict__ w, int n_u16, int* __restrict__ flag)
{
  __shared__ int cnt;
  if (threadIdx.x == 0) cnt = 0;
  __syncthreads();
  int local = 0;
  for (int i = threadIdx.x * 2; i < n_u16; i += 512) {
    unsigned e = (w[i] >> 7) & 0xFF;
    if (e >= 0xF0) local++;
  }
  atomicAdd(&cnt, local);
  __syncthreads();
  if (threadIdx.x == 0) *flag = (cnt > 64) ? 1 : 0;
}

// ---------------------------------------------------------------------------
// One merged kernel canonicalizing all 14 weight tensors to bf16 in ws.
// ---------------------------------------------------------------------------
__global__ __launch_bounds__(256) void convertw_kernel(
    const void* s0, const void* s1, const void* s2, const void* s3,
    const void* s4, const void* s5, const void* s6, const void* s7,
    const void* s8, const void* s9, const void* s10, const void* s11,
    const void* s12, const void* s13,
    unsigned short* __restrict__ wbuf, const int* __restrict__ flag)
{
  const void* srcs[14] = {s0, s1, s2, s3, s4, s5, s6, s7, s8, s9, s10, s11, s12, s13};
  const int woff[14] = {0,      49152,  114688, 115200, 164352, 229888,
                        230400, 361472, 427008, 427520, 558592, 624128,
                        624640, 624896};
  const int wlen[14] = {49152, 65536, 512, 49152, 65536, 512,
                        131072, 65536, 512, 131072, 65536, 512, 256, 1};
  int sb = 0, i = 0;
  for (i = 0; i < 14; ++i) {
    int nb = (wlen[i] + 1023) >> 10;
    if ((int)blockIdx.x < sb + nb) break;
    sb += nb;
  }
  const int base = ((int)blockIdx.x - sb) * 1024 + (int)threadIdx.x * 4;
  unsigned short* dst = wbuf + woff[i];
  if (*flag) {
    const float* s = (const float*)srcs[i];
#pragma unroll
    for (int j = 0; j < 4; ++j)
      if (base + j < wlen[i]) dst[base + j] = f2bf(s[base + j]);
  } else {
    const unsigned short* s = (const unsigned short*)srcs[i];
#pragma unroll
    for (int j = 0; j < 4; ++j)
      if (base + j < wlen[i]) dst[base + j] = s[base + j];
  }
}

// ---------------------------------------------------------------------------
// 512-thread GEMM body; one block covers one (t, dir-slice): 8 waves x 64
// cols = 512 cols. Z output bf16, BG-MAJOR [t][dir][bg][512 cols][16 b].
// ---------------------------------------------------------------------------
template <int K>
__device__ __forceinline__ void gemm512_body(
    unsigned short* As, int t, int slice,
    const void* __restrict__ A, size_t a_off, int dyn,
    const int* __restrict__ flag,
    const unsigned short* __restrict__ Bf, const unsigned short* __restrict__ Bb,
    const unsigned short* __restrict__ biasf, const unsigned short* __restrict__ biasb,
    unsigned short* __restrict__ Z)
{
  constexpr int RS = K + 8;
  const int tid = threadIdx.x, w = tid >> 6, lane = tid & 63;
  const int q = lane >> 4, cc = lane & 15;
  constexpr int K8 = K / 8;
  const int use32 = dyn ? *flag : 0;   // wave-uniform
  if (use32) {
    const float* Arow = (const float*)A + a_off + (size_t)t * 64 * K;
    for (int ci = tid; ci < 64 * K8; ci += 512) {
      int r_ = ci / K8, c8 = ci % K8;
      const float* p = Arow + r_ * K + c8 * 8;
      floatx4 x0 = *(const floatx4*)p;
      floatx4 x1 = *(const floatx4*)(p + 4);
      short8 s;
#pragma unroll
      for (int j = 0; j < 4; ++j) {
        s[j] = (short)f2bf(x0[j]);
        s[4 + j] = (short)f2bf(x1[j]);
      }
      *(short8*)&As[r_ * RS + c8 * 8] = s;
    }
  } else {
    const unsigned short* Arow = (const unsigned short*)A + a_off + (size_t)t * 64 * K;
    for (int ci = tid; ci < 64 * K8; ci += 512) {
      int r_ = ci / K8, c8 = ci % K8;
      *(short8*)&As[r_ * RS + c8 * 8] = *(const short8*)&Arow[r_ * K + c8 * 8];
    }
  }
  __syncthreads();
  const unsigned short* Bp    = slice ? Bb : Bf;
  const unsigned short* biasp = slice ? biasb : biasf;
  const int cb = w * 64;          // within-dir col base
  const int dslab = slice * 4;
  floatx4 acc[4][4];
#pragma unroll
  for (int m = 0; m < 4; ++m)
#pragma unroll
    for (int n = 0; n < 4; ++n)
#pragma unroll
      for (int r = 0; r < 4; ++r) acc[m][n][r] = 0.f;
#pragma unroll
  for (int ks = 0; ks < K / 32; ++ks) {
    short8 af[4], bfr[4];
#pragma unroll
    for (int m = 0; m < 4; ++m)
      af[m] = *(const short8*)&As[(m * 16 + cc) * RS + ks * 32 + q * 8];
#pragma unroll
    for (int n = 0; n < 4; ++n)
      bfr[n] = *(const short8*)&Bp[(size_t)(cb + n * 16 + cc) * K + ks * 32 + q * 8];
#pragma unroll
    for (int m = 0; m < 4; ++m)
#pragma unroll
      for (int n = 0; n < 4; ++n)
        acc[m][n] = mfma16(af[m], bfr[n], acc[m][n]);
  }
#pragma unroll
  for (int n = 0; n < 4; ++n) {
    const int col = cb + n * 16 + cc;
    const float bv = bf2f(biasp[col]);
#pragma unroll
    for (int m = 0; m < 4; ++m) {
      short4v zv;
#pragma unroll
      for (int r = 0; r < 4; ++r)
        zv[r] = (short)f2bf(acc[m][n][r] + bv);
      *(short4v*)&Z[((size_t)t * 8 + dslab + m) * 8192 + col * 16 + q * 4] = zv;
    }
  }
}

// ---------------------------------------------------------------------------
// 512-thread FC body: block idx covers timesteps idx*2 and idx*2+1.
// ---------------------------------------------------------------------------
__device__ __forceinline__ void fc512_body(
    int idx, int steps, const unsigned short* __restrict__ ys1,
    const unsigned short* __restrict__ fcw, const unsigned short* __restrict__ fcb,
    void* __restrict__ out, size_t out_off, const int* __restrict__ flag)
{
  const int tid = threadIdx.x;
  const int w = tid >> 6, lane = tid & 63;
  const int t = idx * 2 + (w >> 2);
  if (t >= steps) return;
  const int w4 = w & 3;
  const int o = lane & 15, q = lane >> 4;
  const int b = w4 * 16 + o;
  const unsigned short* rp = ys1 + ((size_t)t * 64 + b) * 256 + q * 64;
  float s = 0.f;
#pragma unroll
  for (int j = 0; j < 16; ++j) {
    short4v v = *(const short4v*)(rp + j * 4);
    const unsigned short* wp = fcw + q * 64 + j * 4;
#pragma unroll
    for (int k = 0; k < 4; ++k) s += bf2f((unsigned short)v[k]) * bf2f(wp[k]);
  }
  s += __shfl_xor(s, 16, 64);
  s += __shfl_xor(s, 32, 64);
  if (q == 0) {
    const float v = fsig(s + bf2f(fcb[0]));
    const size_t oidx = out_off + (size_t)t * 64 + b;
    if (*flag) ((float*)out)[oidx] = v;
    else       ((unsigned short*)out)[oidx] = f2bf(v);
  }
}

// ---------------------------------------------------------------------------
// Fused pipeline kernel. Blocks 0..15: recurrence (ctx a = L0 chunk c,
// ctx b = L1 chunk c-2). Blocks 16..16+2C: g96(chunk c+1) -> Z0[(c+1)&1].
// Blocks ..+2C: g256(chunk c-1) reading ys0[(c-1)&1] -> Z1[(c-1)&1].
// Blocks ..+(C+1)/2: fc(chunk c-3) reading ys1[(c-3)&1]. All worker reads/
// writes are parity-disjoint from the concurrent rec reads/writes.
// rec: Z bf16 BG-MAJOR [t][dir][bg][512][16]; Z(t+1) prefetched at top of
// step t; LDS-only in-loop barrier; fused rational gate math (round 10).
// Z overreads one step past the end -> next mapped ws buffer (never consumed).
// ---------------------------------------------------------------------------
__global__ __launch_bounds__(512, 2) void rec_kernel(
    const unsigned short* __restrict__ Za, const unsigned short* __restrict__ whhfa,
    const unsigned short* __restrict__ whhba,
    unsigned short* __restrict__ ysa, float* __restrict__ ca,
    unsigned short* __restrict__ ha, int inita, int acta,
    const unsigned short* __restrict__ Zb, const unsigned short* __restrict__ whhfb,
    const unsigned short* __restrict__ whhbb,
    unsigned short* __restrict__ ysb, float* __restrict__ cb_,
    unsigned short* __restrict__ hb, int initb, int actb,
    int steps,
    const void* __restrict__ x, size_t x_off, int do96, const int* __restrict__ flag,
    const unsigned short* __restrict__ wih0f, const unsigned short* __restrict__ wih0b,
    const unsigned short* __restrict__ b0f, const unsigned short* __restrict__ b0b,
    unsigned short* __restrict__ Z0n,
    const unsigned short* __restrict__ ys0g, int do256,
    const unsigned short* __restrict__ wih1f, const unsigned short* __restrict__ wih1b,
    const unsigned short* __restrict__ b1f, const unsigned short* __restrict__ b1b,
    unsigned short* __restrict__ Z1n,
    const unsigned short* __restrict__ fcsrc,
    const unsigned short* __restrict__ fcw, const unsigned short* __restrict__ fcb,
    void* __restrict__ out, size_t fc_off, int fcn)
{
  // 64 KB LDS: caps residency at 2 blocks/CU so at most one transient worker
  // shares a rec CU. Overlaid: rec hbuf (8.7 KB) / gemm As (<= 33.8 KB).
  __shared__ __align__(16) unsigned char smem[65536];
  const int bx = blockIdx.x;
  const int g96n = steps * 2;

  if (bx >= 16) {
    const int wi = bx - 16;
    if (wi < g96n) {                       // embedded gemm96 (next chunk L0)
      if (!do96) return;
      gemm512_body<96>((unsigned short*)smem, wi >> 1, wi & 1, x, x_off, 1,
                       flag, wih0f, wih0b, b0f, b0b, Z0n);
    } else if (wi < 2 * g96n) {            // embedded gemm256 (L1 chunk c-1)
      if (!do256) return;
      const int idx = wi - g96n;
      gemm512_body<256>((unsigned short*)smem, idx >> 1, idx & 1, ys0g, 0, 0,
                        flag, wih1f, wih1b, b1f, b1b, Z1n);
    } else {                               // embedded fc (chunk c-3)
      if (fcn <= 0) return;
      fc512_body(wi - 2 * g96n, steps, fcsrc, fcw, fcb, out, fc_off, flag);
    }
    return;
  }

  // ---- recurrence path ----
  const int blk = bx;
  if (blk < 8 ? !acta : !actb) return;
  unsigned short (*hbuf)[16][136] = (unsigned short(*)[16][136])smem;

  const unsigned short* Z;
  const unsigned short* whhF;
  const unsigned short* whhB;
  unsigned short* ys;
  float* cst;
  unsigned short* hst;
  int init;
  if (blk < 8) {
    Z = Za; whhF = whhfa; whhB = whhba; ys = ysa; cst = ca; hst = ha; init = inita;
  } else {
    Z = Zb; whhF = whhfb; whhB = whhbb; ys = ysb; cst = cb_; hst = hb; init = initb;
  }
  const int d = (blk >> 2) & 1, bg = blk & 3;
  const unsigned short* whh = d ? whhB : whhF;

  const int tid = threadIdx.x;
  const int w = tid >> 6, lane = tid & 63, q = lane >> 4, cc = lane & 15;
  const int u = w * 16 + cc;

  // Whh as MFMA B-fragments, register-resident (64 regs).
  short8 bfrag[4][4];
#pragma unroll
  for (int g = 0; g < 4; ++g)
#pragma unroll
    for (int k = 0; k < 4; ++k)
      bfrag[g][k] = *(const short8*)(whh + (size_t)(g * 128 + u) * 128 + k * 32 + q * 8);

  float creg[4];
  const int row = tid >> 5;          // 0..15
  const int col4 = (tid & 31) * 4;   // 0..124
  if (init) {
#pragma unroll
    for (int r = 0; r < 4; ++r) creg[r] = 0.f;
    short4v zz = {0, 0, 0, 0};
    *(short4v*)&hbuf[0][row][col4] = zz;
  } else {
#pragma unroll
    for (int r = 0; r < 4; ++r)
      creg[r] = cst[(size_t)(d * 64 + bg * 16 + q * 4 + r) * 128 + u];
    *(short4v*)&hbuf[0][row][col4] =
        *(const short4v*)(hst + (size_t)(d * 64 + bg * 16 + row) * 128 + col4);
  }
  __syncthreads();

  const size_t zbase = (size_t)(d * 4 + bg) * 8192 + u * 16 + q * 4;
  short4v zcur[4];
#pragma unroll
  for (int g = 0; g < 4; ++g)
    zcur[g] = *(const short4v*)(Z + zbase + g * 2048);

  for (int t = 0; t < steps; ++t) {
    const int cur = t & 1, nxt = cur ^ 1;
    // prefetch Z(t+1) FIRST (unclamped; tail overread is dead), pinned
    const unsigned short* ztn = Z + (size_t)(t + 1) * 65536 + zbase;
    short4v zpf[4];
#pragma unroll
    for (int g = 0; g < 4; ++g)
      zpf[g] = *(const short4v*)(ztn + g * 2048);
    __builtin_amdgcn_sched_barrier(0);

    floatx4 acc[4];
#pragma unroll
    for (int g = 0; g < 4; ++g)
#pragma unroll
      for (int r = 0; r < 4; ++r)
        acc[g][r] = bf2f((unsigned short)zcur[g][r]);

    short8 af[4];
#pragma unroll
    for (int k = 0; k < 4; ++k)
      af[k] = *(const short8*)&hbuf[cur][cc][k * 32 + q * 8];
#pragma unroll
    for (int g = 0; g < 4; ++g)
#pragma unroll
      for (int k = 0; k < 4; ++k)
        acc[g] = mfma16(af[k], bfrag[g][k], acc[g]);

    // fused pointwise (round 10): 5 exp + 3 rcp per (b,u) pair
#pragma unroll
    for (int r = 0; r < 4; ++r) {
      float zi = acc[0][r], zf = acc[1][r], zg = acc[2][r], zo = acc[3][r];
      float ei = fast_exp2(LOG2E * zi);
      float eg = fast_exp2((2.0f * LOG2E) * zg);
      float ef = fast_exp2(LOG2E * zf);
      float it = ei * (eg - 1.0f) * fast_rcp((1.0f + ei) * (1.0f + eg));
      float sf = ef * fast_rcp(1.0f + ef);
      float cn = sf * creg[r] + it;
      creg[r] = cn;
      float eo = fast_exp2(LOG2E * zo);
      float ec = fast_exp2(fminf((2.0f * LOG2E) * cn, 88.0f));
      float h = eo * (ec - 1.0f) * fast_rcp((1.0f + eo) * (1.0f + ec));
      hbuf[nxt][q * 4 + r][u] = f2bf(h);
    }
    // LDS-only barrier: drain ds ops, leave vmcnt (ys store + Z prefetch)
    asm volatile("s_waitcnt lgkmcnt(0)\n\ts_barrier" ::: "memory");
    unsigned short* yd = ys + (size_t)(t * 64 + bg * 16 + row) * 256 + d * 128 + col4;
    *(short4v*)yd = *(const short4v*)&hbuf[nxt][row][col4];
#pragma unroll
    for (int g = 0; g < 4; ++g) zcur[g] = zpf[g];
  }
#pragma unroll
  for (int r = 0; r < 4; ++r)
    cst[(size_t)(d * 64 + bg * 16 + q * 4 + r) * 128 + u] = creg[r];
  const int fin = steps & 1;
  *(short4v*)(hst + (size_t)(d * 64 + bg * 16 + row) * 128 + col4) =
      *(const short4v*)&hbuf[fin][row][col4];
}

// ---------------------------------------------------------------------------
// Standalone gemm96 (chunk 0 prologue). Grid 2C x 512.
// ---------------------------------------------------------------------------
__global__ __launch_bounds__(512) void g96_kernel(
    const void* __restrict__ x, size_t x_off, const int* __restrict__ flag,
    const unsigned short* __restrict__ Bf, const unsigned short* __restrict__ Bb,
    const unsigned short* __restrict__ biasf, const unsigned short* __restrict__ biasb,
    unsigned short* __restrict__ Z)
{
  __shared__ __align__(16) unsigned short As[64 * 104];
  gemm512_body<96>(As, blockIdx.x >> 1, blockIdx.x & 1, x, x_off, 1, flag,
                   Bf, Bb, biasf, biasb, Z);
}

// ---------------------------------------------------------------------------
// Standalone FC (final chunk). One wave per (t,b).
// ---------------------------------------------------------------------------
__global__ __launch_bounds__(256) void fc_kernel(
    const unsigned short* __restrict__ ys,
    const unsigned short* __restrict__ fcw,
    const unsigned short* __restrict__ fcb,
    void* __restrict__ out, size_t out_off, int n,
    const int* __restrict__ flag)
{
  const int gw = (int)((blockIdx.x * 256 + threadIdx.x) >> 6);
  const int lane = threadIdx.x & 63;
  if (gw >= n) return;
  const unsigned short* rp = ys + (size_t)gw * 256 + lane * 4;
  float s = 0.f;
#pragma unroll
  for (int i = 0; i < 4; ++i) s += bf2f(rp[i]) * bf2f(fcw[lane * 4 + i]);
#pragma unroll
  for (int m = 32; m >= 1; m >>= 1) s += __shfl_xor(s, m, 64);
  if (lane == 0) {
    const float v = fsig(s + bf2f(fcb[0]));
    if (*flag) ((float*)out)[out_off + gw] = v;
    else       ((unsigned short*)out)[out_off + gw] = f2bf(v);
  }
}

extern "C" void kernel_launch(void* const* d_in, const int* in_sizes, int n_in,
                              void* d_out, int out_size, void* d_ws, size_t ws_size,
                              hipStream_t stream)
{
  (void)in_sizes; (void)n_in; (void)out_size;
  const int S = 4096;

  int* flag = (int*)d_ws;
  unsigned short* wbuf = (unsigned short*)((char*)d_ws + 256);
  static const int woff[14] = {0,      49152,  114688, 115200, 164352, 229888,
                               230400, 361472, 427008, 427520, 558592, 624128,
                               624640, 624896};
  const size_t wbuf_end = 256 + 1250304;  // bytes

  // Buffers (all double): Z0 2*C*131072 B, Z1 2*C*131072, ys0 2*C*32768,
  // ys1 2*C*32768 -> C*655360 B. Fixed: wbuf_end + state 196608.
  int C = 1;
  for (int cand = 256; cand >= 1; cand >>= 1) {
    size_t need = (size_t)cand * 655360 + wbuf_end + 196608;
    if (need <= ws_size) { C = cand; break; }
  }
  unsigned short* base = (unsigned short*)((char*)d_ws + wbuf_end);
  unsigned short* Z0buf[2] = {base, base + (size_t)C * 65536};
  unsigned short* Z1buf[2] = {base + (size_t)2 * C * 65536, base + (size_t)3 * C * 65536};
  unsigned short* ys0buf[2] = {base + (size_t)4 * C * 65536,
                               base + (size_t)4 * C * 65536 + (size_t)C * 16384};
  unsigned short* ys1buf[2] = {base + (size_t)4 * C * 65536 + (size_t)2 * C * 16384,
                               base + (size_t)4 * C * 65536 + (size_t)3 * C * 16384};
  float* c0 = (float*)(base + (size_t)4 * C * 65536 + (size_t)4 * C * 16384);
  float* c1 = c0 + 16384;
  unsigned short* h0 = (unsigned short*)(c1 + 16384);
  unsigned short* h1 = h0 + 16384;

  const unsigned short* wih0f = wbuf + woff[0];
  const unsigned short* whh0f = wbuf + woff[1];
  const unsigned short* b0f   = wbuf + woff[2];
  const unsigned short* wih0b = wbuf + woff[3];
  const unsigned short* whh0b = wbuf + woff[4];
  const unsigned short* b0b   = wbuf + woff[5];
  const unsigned short* wih1f = wbuf + woff[6];
  const unsigned short* whh1f = wbuf + woff[7];
  const unsigned short* b1f   = wbuf + woff[8];
  const unsigned short* wih1b = wbuf + woff[9];
  const unsigned short* whh1b = wbuf + woff[10];
  const unsigned short* b1b   = wbuf + woff[11];
  const unsigned short* fcw   = wbuf + woff[12];
  const unsigned short* fcb   = wbuf + woff[13];

  detect_kernel<<<1, 256, 0, stream>>>((const unsigned short*)d_in[1], 49152, flag);
  convertw_kernel<<<614, 256, 0, stream>>>(
      d_in[1], d_in[2], d_in[3], d_in[4], d_in[5], d_in[6], d_in[7],
      d_in[8], d_in[9], d_in[10], d_in[11], d_in[12], d_in[13], d_in[14],
      wbuf, flag);

  const int nc = S / C;
  // prologue: gemm96 for chunk 0
  g96_kernel<<<C * 2, 512, 0, stream>>>(d_in[0], 0, flag,
                                        wih0f, wih0b, b0f, b0b, Z0buf[0]);

  const int GX = 16 + 4 * C + (C + 1) / 2;
  for (int c = 0; c <= nc + 1; ++c) {
    const int p = c & 1, pn = (c + 1) & 1;  // pn == (c-1)&1 == (c+1)&1
    rec_kernel<<<GX, 512, 0, stream>>>(
        // ctx a: L0 chunk c
        Z0buf[p], whh0f, whh0b, ys0buf[p], c0, h0, (c == 0) ? 1 : 0,
        (c <= nc - 1) ? 1 : 0,
        // ctx b: L1 chunk c-2
        Z1buf[p], whh1f, whh1b, ys1buf[p], c1, h1, (c == 2) ? 1 : 0,
        (c >= 2) ? 1 : 0,
        C,
        // embedded g96: chunk c+1
        d_in[0], (size_t)(c + 1) * C * 6144, (c <= nc - 2) ? 1 : 0, flag,
        wih0f, wih0b, b0f, b0b, Z0buf[pn],
        // embedded g256: chunk c-1 (ys0[(c-1)&1] -> Z1[(c-1)&1])
        ys0buf[pn], (c >= 1 && c <= nc) ? 1 : 0, wih1f, wih1b, b1f, b1b, Z1buf[pn],
        // embedded fc: chunk c-3 (reads ys1[(c-3)&1])
        ys1buf[pn], fcw, fcb, d_out,
        (c >= 3) ? (size_t)(c - 3) * C * 64 : 0, (c >= 3) ? C * 64 : 0);
  }
  // tail fc: chunk nc-1 (written during rec launch nc+1)
  fc_kernel<<<C * 16, 256, 0, stream>>>(ys1buf[(nc - 1) & 1], fcw, fcb, d_out,
                                        (size_t)(nc - 1) * C * 64, C * 64, flag);
}

// Round 12
// 4986.951 us; speedup vs baseline: 1.0748x; 1.0748x over previous
//
#include <hip/hip_runtime.h>
#include <stdint.h>

typedef short short8 __attribute__((ext_vector_type(8)));
typedef short short4v __attribute__((ext_vector_type(4)));
typedef float floatx4 __attribute__((ext_vector_type(4)));

#define LOG2E 1.44269504088896340736f

__device__ __forceinline__ float bf2f(unsigned short u) {
  unsigned v = ((unsigned)u) << 16;
  return __builtin_bit_cast(float, v);
}
__device__ __forceinline__ unsigned short f2bf(float f) {
  unsigned v = __builtin_bit_cast(unsigned, f);
  v += 0x7FFFu + ((v >> 16) & 1u);   // RNE
  return (unsigned short)(v >> 16);
}
__device__ __forceinline__ float fast_exp2(float x) {
#if __has_builtin(__builtin_amdgcn_exp2f)
  return __builtin_amdgcn_exp2f(x);
#else
  return exp2f(x);
#endif
}
__device__ __forceinline__ float fast_rcp(float x) {
#if __has_builtin(__builtin_amdgcn_rcpf)
  return __builtin_amdgcn_rcpf(x);
#else
  return 1.0f / x;
#endif
}
__device__ __forceinline__ float fsig(float x) {
  return fast_rcp(1.0f + fast_exp2(-LOG2E * x));
}
__device__ __forceinline__ floatx4 mfma16(short8 a, short8 b, floatx4 c) {
  return __builtin_amdgcn_mfma_f32_16x16x32_bf16(a, b, c, 0, 0, 0);
}

// ---------------------------------------------------------------------------
// Dtype detection: f32 buffers show even-u16 "exponent" >= 0xF0 often; bf16
// 0.05-scaled weights never do. flag: 1 = f32, 0 = bf16.
// ---------------------------------------------------------------------------
__global__ __launch_bounds__(256) void detect_kernel(
    const unsigned short* __restrict__ w, int n_u16, int* __restrict__ flag)
{
  __shared__ int cnt;
  if (threadIdx.x == 0) cnt = 0;
  __syncthreads();
  int local = 0;
  for (int i = threadIdx.x * 2; i < n_u16; i += 512) {
    unsigned e = (w[i] >> 7) & 0xFF;
    if (e >= 0xF0) local++;
  }
  atomicAdd(&cnt, local);
  __syncthreads();
  if (threadIdx.x == 0) *flag = (cnt > 64) ? 1 : 0;
}

// ---------------------------------------------------------------------------
// One merged kernel canonicalizing all 14 weight tensors to bf16 in ws.
// ---------------------------------------------------------------------------
__global__ __launch_bounds__(256) void convertw_kernel(
    const void* s0, const void* s1, const void* s2, const void* s3,
    const void* s4, const void* s5, const void* s6, const void* s7,
    const void* s8, const void* s9, const void* s10, const void* s11,
    const void* s12, const void* s13,
    unsigned short* __restrict__ wbuf, const int* __restrict__ flag)
{
  const void* srcs[14] = {s0, s1, s2, s3, s4, s5, s6, s7, s8, s9, s10, s11, s12, s13};
  const int woff[14] = {0,      49152,  114688, 115200, 164352, 229888,
                        230400, 361472, 427008, 427520, 558592, 624128,
                        624640, 624896};
  const int wlen[14] = {49152, 65536, 512, 49152, 65536, 512,
                        131072, 65536, 512, 131072, 65536, 512, 256, 1};
  int sb = 0, i = 0;
  for (i = 0; i < 14; ++i) {
    int nb = (wlen[i] + 1023) >> 10;
    if ((int)blockIdx.x < sb + nb) break;
    sb += nb;
  }
  const int base = ((int)blockIdx.x - sb) * 1024 + (int)threadIdx.x * 4;
  unsigned short* dst = wbuf + woff[i];
  if (*flag) {
    const float* s = (const float*)srcs[i];
#pragma unroll
    for (int j = 0; j < 4; ++j)
      if (base + j < wlen[i]) dst[base + j] = f2bf(s[base + j]);
  } else {
    const unsigned short* s = (const unsigned short*)srcs[i];
#pragma unroll
    for (int j = 0; j < 4; ++j)
      if (base + j < wlen[i]) dst[base + j] = s[base + j];
  }
}

// ---------------------------------------------------------------------------
// GEMM body for 1024-thread blocks: all 16 waves stage A into LDS, waves 0..7
// (tid<512) compute 512 cols (8 waves x 64). Z output bf16, BG-MAJOR
// [t][dir][bg][512 cols][16 b].
// ---------------------------------------------------------------------------
template <int K>
__device__ __forceinline__ void gemm1024_body(
    unsigned short* As, int t, int slice,
    const void* __restrict__ A, size_t a_off, int dyn,
    const int* __restrict__ flag,
    const unsigned short* __restrict__ Bf, const unsigned short* __restrict__ Bb,
    const unsigned short* __restrict__ biasf, const unsigned short* __restrict__ biasb,
    unsigned short* __restrict__ Z)
{
  constexpr int RS = K + 8;
  const int tid = threadIdx.x, lane = tid & 63;
  const int q = lane >> 4, cc = lane & 15;
  constexpr int K8 = K / 8;
  const int use32 = dyn ? *flag : 0;   // wave-uniform
  if (use32) {
    const float* Arow = (const float*)A + a_off + (size_t)t * 64 * K;
    for (int ci = tid; ci < 64 * K8; ci += 1024) {
      int r_ = ci / K8, c8 = ci % K8;
      const float* p = Arow + r_ * K + c8 * 8;
      floatx4 x0 = *(const floatx4*)p;
      floatx4 x1 = *(const floatx4*)(p + 4);
      short8 s;
#pragma unroll
      for (int j = 0; j < 4; ++j) {
        s[j] = (short)f2bf(x0[j]);
        s[4 + j] = (short)f2bf(x1[j]);
      }
      *(short8*)&As[r_ * RS + c8 * 8] = s;
    }
  } else {
    const unsigned short* Arow = (const unsigned short*)A + a_off + (size_t)t * 64 * K;
    for (int ci = tid; ci < 64 * K8; ci += 1024) {
      int r_ = ci / K8, c8 = ci % K8;
      *(short8*)&As[r_ * RS + c8 * 8] = *(const short8*)&Arow[r_ * K + c8 * 8];
    }
  }
  __syncthreads();
  if (tid >= 512) return;                // waves 8..15 done (no more barriers)
  const int w = tid >> 6;
  const unsigned short* Bp    = slice ? Bb : Bf;
  const unsigned short* biasp = slice ? biasb : biasf;
  const int cb = w * 64;
  const int dslab = slice * 4;
  floatx4 acc[4][4];
#pragma unroll
  for (int m = 0; m < 4; ++m)
#pragma unroll
    for (int n = 0; n < 4; ++n)
#pragma unroll
      for (int r = 0; r < 4; ++r) acc[m][n][r] = 0.f;
#pragma unroll
  for (int ks = 0; ks < K / 32; ++ks) {
    short8 af[4], bfr[4];
#pragma unroll
    for (int m = 0; m < 4; ++m)
      af[m] = *(const short8*)&As[(m * 16 + cc) * RS + ks * 32 + q * 8];
#pragma unroll
    for (int n = 0; n < 4; ++n)
      bfr[n] = *(const short8*)&Bp[(size_t)(cb + n * 16 + cc) * K + ks * 32 + q * 8];
#pragma unroll
    for (int m = 0; m < 4; ++m)
#pragma unroll
      for (int n = 0; n < 4; ++n)
        acc[m][n] = mfma16(af[m], bfr[n], acc[m][n]);
  }
#pragma unroll
  for (int n = 0; n < 4; ++n) {
    const int col = cb + n * 16 + cc;
    const float bv = bf2f(biasp[col]);
#pragma unroll
    for (int m = 0; m < 4; ++m) {
      short4v zv;
#pragma unroll
      for (int r = 0; r < 4; ++r)
        zv[r] = (short)f2bf(acc[m][n][r] + bv);
      *(short4v*)&Z[((size_t)t * 8 + dslab + m) * 8192 + col * 16 + q * 4] = zv;
    }
  }
}

// ---------------------------------------------------------------------------
// FC body (tid<512): block idx covers timesteps idx*2 and idx*2+1.
// ---------------------------------------------------------------------------
__device__ __forceinline__ void fc512_body(
    int idx, int steps, const unsigned short* __restrict__ ys1,
    const unsigned short* __restrict__ fcw, const unsigned short* __restrict__ fcb,
    void* __restrict__ out, size_t out_off, const int* __restrict__ flag)
{
  const int tid = threadIdx.x;
  const int w = tid >> 6, lane = tid & 63;
  const int t = idx * 2 + (w >> 2);
  if (t >= steps) return;
  const int w4 = w & 3;
  const int o = lane & 15, q = lane >> 4;
  const int b = w4 * 16 + o;
  const unsigned short* rp = ys1 + ((size_t)t * 64 + b) * 256 + q * 64;
  float s = 0.f;
#pragma unroll
  for (int j = 0; j < 16; ++j) {
    short4v v = *(const short4v*)(rp + j * 4);
    const unsigned short* wp = fcw + q * 64 + j * 4;
#pragma unroll
    for (int k = 0; k < 4; ++k) s += bf2f((unsigned short)v[k]) * bf2f(wp[k]);
  }
  s += __shfl_xor(s, 16, 64);
  s += __shfl_xor(s, 32, 64);
  if (q == 0) {
    const float v = fsig(s + bf2f(fcb[0]));
    const size_t oidx = out_off + (size_t)t * 64 + b;
    if (*flag) ((float*)out)[oidx] = v;
    else       ((unsigned short*)out)[oidx] = f2bf(v);
  }
}

// ---------------------------------------------------------------------------
// Fused pipeline kernel, 1024-thread blocks (16 waves = full CU at VGPR>64,
// pinned by the v99 clobber) -> one rec block OWNS its CU; workers can never
// co-reside with rec. Blocks 0..15: recurrence (waves 0..7 compute, waves
// 8..15 are barrier companions). Blocks 16+: g96(c+1), g256(c-1), fc(c-3)
// workers (parity-disjoint buffers, same as round 11).
// rec: Z bf16 BG-MAJOR [t][dir][bg][512][16]; Z(t+1) prefetched at top of
// step t; LDS-only in-loop barrier; fused rational gate math.
// ---------------------------------------------------------------------------
__global__ __launch_bounds__(1024, 4) void rec_kernel(
    const unsigned short* __restrict__ Za, const unsigned short* __restrict__ whhfa,
    const unsigned short* __restrict__ whhba,
    unsigned short* __restrict__ ysa, float* __restrict__ ca,
    unsigned short* __restrict__ ha, int inita, int acta,
    const unsigned short* __restrict__ Zb, const unsigned short* __restrict__ whhfb,
    const unsigned short* __restrict__ whhbb,
    unsigned short* __restrict__ ysb, float* __restrict__ cb_,
    unsigned short* __restrict__ hb, int initb, int actb,
    int steps,
    const void* __restrict__ x, size_t x_off, int do96, const int* __restrict__ flag,
    const unsigned short* __restrict__ wih0f, const unsigned short* __restrict__ wih0b,
    const unsigned short* __restrict__ b0f, const unsigned short* __restrict__ b0b,
    unsigned short* __restrict__ Z0n,
    const unsigned short* __restrict__ ys0g, int do256,
    const unsigned short* __restrict__ wih1f, const unsigned short* __restrict__ wih1b,
    const unsigned short* __restrict__ b1f, const unsigned short* __restrict__ b1b,
    unsigned short* __restrict__ Z1n,
    const unsigned short* __restrict__ fcsrc,
    const unsigned short* __restrict__ fcw, const unsigned short* __restrict__ fcb,
    void* __restrict__ out, size_t fc_off, int fcn)
{
  __shared__ __align__(16) unsigned char smem[65536];
  // Pin kernel VGPR count above 64 so occupancy = 16 waves/CU: one
  // 1024-thread block fills the CU; no second block can land on a rec CU.
  asm volatile("" ::: "v99");
  const int bx = blockIdx.x;
  const int g96n = steps * 2;

  if (bx >= 16) {
    const int wi = bx - 16;
    if (wi < g96n) {                       // g96 (next chunk L0)
      if (!do96) return;
      gemm1024_body<96>((unsigned short*)smem, wi >> 1, wi & 1, x, x_off, 1,
                        flag, wih0f, wih0b, b0f, b0b, Z0n);
    } else if (wi < 2 * g96n) {            // g256 (L1 chunk c-1)
      if (!do256) return;
      const int idx = wi - g96n;
      gemm1024_body<256>((unsigned short*)smem, idx >> 1, idx & 1, ys0g, 0, 0,
                         flag, wih1f, wih1b, b1f, b1b, Z1n);
    } else {                               // fc (chunk c-3)
      if (fcn <= 0) return;
      if (threadIdx.x < 512)
        fc512_body(wi - 2 * g96n, steps, fcsrc, fcw, fcb, out, fc_off, flag);
    }
    return;
  }

  // ---- recurrence path ----
  const int blk = bx;
  if (blk < 8 ? !acta : !actb) return;
  const int tid = threadIdx.x;
  if (tid >= 512) {
    // barrier companions: occupy waves 8..15 for the whole kernel so the CU
    // has no free slots; match compute waves' barrier count exactly.
    __syncthreads();
    for (int t = 0; t < steps; ++t)
      asm volatile("s_waitcnt lgkmcnt(0)\n\ts_barrier" ::: "memory");
    return;
  }
  unsigned short (*hbuf)[16][136] = (unsigned short(*)[16][136])smem;

  const unsigned short* Z;
  const unsigned short* whhF;
  const unsigned short* whhB;
  unsigned short* ys;
  float* cst;
  unsigned short* hst;
  int init;
  if (blk < 8) {
    Z = Za; whhF = whhfa; whhB = whhba; ys = ysa; cst = ca; hst = ha; init = inita;
  } else {
    Z = Zb; whhF = whhfb; whhB = whhbb; ys = ysb; cst = cb_; hst = hb; init = initb;
  }
  const int d = (blk >> 2) & 1, bg = blk & 3;
  const unsigned short* whh = d ? whhB : whhF;

  const int w = tid >> 6, lane = tid & 63, q = lane >> 4, cc = lane & 15;
  const int u = w * 16 + cc;

  // Whh as MFMA B-fragments, register-resident (64 regs).
  short8 bfrag[4][4];
#pragma unroll
  for (int g = 0; g < 4; ++g)
#pragma unroll
    for (int k = 0; k < 4; ++k)
      bfrag[g][k] = *(const short8*)(whh + (size_t)(g * 128 + u) * 128 + k * 32 + q * 8);

  float creg[4];
  const int row = tid >> 5;          // 0..15
  const int col4 = (tid & 31) * 4;   // 0..124
  if (init) {
#pragma unroll
    for (int r = 0; r < 4; ++r) creg[r] = 0.f;
    short4v zz = {0, 0, 0, 0};
    *(short4v*)&hbuf[0][row][col4] = zz;
  } else {
#pragma unroll
    for (int r = 0; r < 4; ++r)
      creg[r] = cst[(size_t)(d * 64 + bg * 16 + q * 4 + r) * 128 + u];
    *(short4v*)&hbuf[0][row][col4] =
        *(const short4v*)(hst + (size_t)(d * 64 + bg * 16 + row) * 128 + col4);
  }
  __syncthreads();

  const size_t zbase = (size_t)(d * 4 + bg) * 8192 + u * 16 + q * 4;
  short4v zcur[4];
#pragma unroll
  for (int g = 0; g < 4; ++g)
    zcur[g] = *(const short4v*)(Z + zbase + g * 2048);

  for (int t = 0; t < steps; ++t) {
    const int cur = t & 1, nxt = cur ^ 1;
    // prefetch Z(t+1) FIRST (tail overread is dead data in mapped ws), pinned
    const unsigned short* ztn = Z + (size_t)(t + 1) * 65536 + zbase;
    short4v zpf[4];
#pragma unroll
    for (int g = 0; g < 4; ++g)
      zpf[g] = *(const short4v*)(ztn + g * 2048);
    __builtin_amdgcn_sched_barrier(0);

    floatx4 acc[4];
#pragma unroll
    for (int g = 0; g < 4; ++g)
#pragma unroll
      for (int r = 0; r < 4; ++r)
        acc[g][r] = bf2f((unsigned short)zcur[g][r]);

    short8 af[4];
#pragma unroll
    for (int k = 0; k < 4; ++k)
      af[k] = *(const short8*)&hbuf[cur][cc][k * 32 + q * 8];
#pragma unroll
    for (int g = 0; g < 4; ++g)
#pragma unroll
      for (int k = 0; k < 4; ++k)
        acc[g] = mfma16(af[k], bfrag[g][k], acc[g]);

    // fused pointwise: 5 exp + 3 rcp per (b,u) pair
#pragma unroll
    for (int r = 0; r < 4; ++r) {
      float zi = acc[0][r], zf = acc[1][r], zg = acc[2][r], zo = acc[3][r];
      float ei = fast_exp2(LOG2E * zi);
      float eg = fast_exp2((2.0f * LOG2E) * zg);
      float ef = fast_exp2(LOG2E * zf);
      float it = ei * (eg - 1.0f) * fast_rcp((1.0f + ei) * (1.0f + eg));
      float sf = ef * fast_rcp(1.0f + ef);
      float cn = sf * creg[r] + it;
      creg[r] = cn;
      float eo = fast_exp2(LOG2E * zo);
      float ec = fast_exp2(fminf((2.0f * LOG2E) * cn, 88.0f));
      float h = eo * (ec - 1.0f) * fast_rcp((1.0f + eo) * (1.0f + ec));
      hbuf[nxt][q * 4 + r][u] = f2bf(h);
    }
    // LDS-only barrier: drain ds ops, leave vmcnt (ys store + Z prefetch)
    asm volatile("s_waitcnt lgkmcnt(0)\n\ts_barrier" ::: "memory");
    unsigned short* yd = ys + (size_t)(t * 64 + bg * 16 + row) * 256 + d * 128 + col4;
    *(short4v*)yd = *(const short4v*)&hbuf[nxt][row][col4];
#pragma unroll
    for (int g = 0; g < 4; ++g) zcur[g] = zpf[g];
  }
#pragma unroll
  for (int r = 0; r < 4; ++r)
    cst[(size_t)(d * 64 + bg * 16 + q * 4 + r) * 128 + u] = creg[r];
  const int fin = steps & 1;
  *(short4v*)(hst + (size_t)(d * 64 + bg * 16 + row) * 128 + col4) =
      *(const short4v*)&hbuf[fin][row][col4];
}

// ---------------------------------------------------------------------------
// Standalone gemm96 (chunk 0 prologue). Grid 2C x 1024.
// ---------------------------------------------------------------------------
__global__ __launch_bounds__(1024) void g96_kernel(
    const void* __restrict__ x, size_t x_off, const int* __restrict__ flag,
    const unsigned short* __restrict__ Bf, const unsigned short* __restrict__ Bb,
    const unsigned short* __restrict__ biasf, const unsigned short* __restrict__ biasb,
    unsigned short* __restrict__ Z)
{
  __shared__ __align__(16) unsigned short As[64 * 104];
  gemm1024_body<96>(As, blockIdx.x >> 1, blockIdx.x & 1, x, x_off, 1, flag,
                    Bf, Bb, biasf, biasb, Z);
}

// ---------------------------------------------------------------------------
// Standalone FC (final chunk). One wave per (t,b).
// ---------------------------------------------------------------------------
__global__ __launch_bounds__(256) void fc_kernel(
    const unsigned short* __restrict__ ys,
    const unsigned short* __restrict__ fcw,
    const unsigned short* __restrict__ fcb,
    void* __restrict__ out, size_t out_off, int n,
    const int* __restrict__ flag)
{
  const int gw = (int)((blockIdx.x * 256 + threadIdx.x) >> 6);
  const int lane = threadIdx.x & 63;
  if (gw >= n) return;
  const unsigned short* rp = ys + (size_t)gw * 256 + lane * 4;
  float s = 0.f;
#pragma unroll
  for (int i = 0; i < 4; ++i) s += bf2f(rp[i]) * bf2f(fcw[lane * 4 + i]);
#pragma unroll
  for (int m = 32; m >= 1; m >>= 1) s += __shfl_xor(s, m, 64);
  if (lane == 0) {
    const float v = fsig(s + bf2f(fcb[0]));
    if (*flag) ((float*)out)[out_off + gw] = v;
    else       ((unsigned short*)out)[out_off + gw] = f2bf(v);
  }
}

extern "C" void kernel_launch(void* const* d_in, const int* in_sizes, int n_in,
                              void* d_out, int out_size, void* d_ws, size_t ws_size,
                              hipStream_t stream)
{
  (void)in_sizes; (void)n_in; (void)out_size;
  const int S = 4096;

  int* flag = (int*)d_ws;
  unsigned short* wbuf = (unsigned short*)((char*)d_ws + 256);
  static const int woff[14] = {0,      49152,  114688, 115200, 164352, 229888,
                               230400, 361472, 427008, 427520, 558592, 624128,
                               624640, 624896};
  const size_t wbuf_end = 256 + 1250304;  // bytes

  // Double buffers: Z0/Z1 2*C*131072 B each, ys0/ys1 2*C*32768 each
  // -> C*655360 B. C capped at 128: wall = (S+2C)*cyc + (S/C)*gap is
  // minimized near C=sqrt(S*gap/2cyc) ~ 117.
  int C = 1;
  for (int cand = 128; cand >= 1; cand >>= 1) {
    size_t need = (size_t)cand * 655360 + wbuf_end + 196608;
    if (need <= ws_size) { C = cand; break; }
  }
  unsigned short* base = (unsigned short*)((char*)d_ws + wbuf_end);
  unsigned short* Z0buf[2] = {base, base + (size_t)C * 65536};
  unsigned short* Z1buf[2] = {base + (size_t)2 * C * 65536, base + (size_t)3 * C * 65536};
  unsigned short* ys0buf[2] = {base + (size_t)4 * C * 65536,
                               base + (size_t)4 * C * 65536 + (size_t)C * 16384};
  unsigned short* ys1buf[2] = {base + (size_t)4 * C * 65536 + (size_t)2 * C * 16384,
                               base + (size_t)4 * C * 65536 + (size_t)3 * C * 16384};
  float* c0 = (float*)(base + (size_t)4 * C * 65536 + (size_t)4 * C * 16384);
  float* c1 = c0 + 16384;
  unsigned short* h0 = (unsigned short*)(c1 + 16384);
  unsigned short* h1 = h0 + 16384;

  const unsigned short* wih0f = wbuf + woff[0];
  const unsigned short* whh0f = wbuf + woff[1];
  const unsigned short* b0f   = wbuf + woff[2];
  const unsigned short* wih0b = wbuf + woff[3];
  const unsigned short* whh0b = wbuf + woff[4];
  const unsigned short* b0b   = wbuf + woff[5];
  const unsigned short* wih1f = wbuf + woff[6];
  const unsigned short* whh1f = wbuf + woff[7];
  const unsigned short* b1f   = wbuf + woff[8];
  const unsigned short* wih1b = wbuf + woff[9];
  const unsigned short* whh1b = wbuf + woff[10];
  const unsigned short* b1b   = wbuf + woff[11];
  const unsigned short* fcw   = wbuf + woff[12];
  const unsigned short* fcb   = wbuf + woff[13];

  detect_kernel<<<1, 256, 0, stream>>>((const unsigned short*)d_in[1], 49152, flag);
  convertw_kernel<<<614, 256, 0, stream>>>(
      d_in[1], d_in[2], d_in[3], d_in[4], d_in[5], d_in[6], d_in[7],
      d_in[8], d_in[9], d_in[10], d_in[11], d_in[12], d_in[13], d_in[14],
      wbuf, flag);

  const int nc = S / C;
  // prologue: gemm96 for chunk 0
  g96_kernel<<<C * 2, 1024, 0, stream>>>(d_in[0], 0, flag,
                                         wih0f, wih0b, b0f, b0b, Z0buf[0]);

  const int GX = 16 + 4 * C + (C + 1) / 2;
  for (int c = 0; c <= nc + 1; ++c) {
    const int p = c & 1, pn = (c + 1) & 1;  // pn == (c-1)&1 == (c+1)&1
    rec_kernel<<<GX, 1024, 0, stream>>>(
        // ctx a: L0 chunk c
        Z0buf[p], whh0f, whh0b, ys0buf[p], c0, h0, (c == 0) ? 1 : 0,
        (c <= nc - 1) ? 1 : 0,
        // ctx b: L1 chunk c-2
        Z1buf[p], whh1f, whh1b, ys1buf[p], c1, h1, (c == 2) ? 1 : 0,
        (c >= 2) ? 1 : 0,
        C,
        // embedded g96: chunk c+1
        d_in[0], (size_t)(c + 1) * C * 6144, (c <= nc - 2) ? 1 : 0, flag,
        wih0f, wih0b, b0f, b0b, Z0buf[pn],
        // embedded g256: chunk c-1 (ys0[(c-1)&1] -> Z1[(c-1)&1])
        ys0buf[pn], (c >= 1 && c <= nc) ? 1 : 0, wih1f, wih1b, b1f, b1b, Z1buf[pn],
        // embedded fc: chunk c-3 (reads ys1[(c-3)&1])
        ys1buf[pn], fcw, fcb, d_out,
        (c >= 3) ? (size_t)(c - 3) * C * 64 : 0, (c >= 3) ? C * 64 : 0);
  }
  // tail fc: chunk nc-1 (written during rec launch nc+1)
  fc_kernel<<<C * 16, 256, 0, stream>>>(ys1buf[(nc - 1) & 1], fcw, fcb, d_out,
                                        (size_t)(nc - 1) * C * 64, C * 64, flag);
}